// Round 1
// baseline (6059.789 us; speedup 1.0000x reference)
//
#include <hip/hip_runtime.h>
#include <hip/hip_bf16.h>

typedef __attribute__((ext_vector_type(8))) short s8;
typedef __attribute__((ext_vector_type(4))) float f4;

using bf16 = __hip_bfloat16;

#define MFMA16(a,b,c) __builtin_amdgcn_mfma_f32_16x16x32_bf16((a),(b),(c),0,0,0)

// ---------------- sizes ----------------
constexpr int SS = 512, BBATCH = 64, HIDN = 512;
constexpr size_t DEC_SZ = (size_t)SS * BBATCH * HIDN;  // 16777216 f32 = 64MiB

// ---------------- ws layout (bytes), total 101 MiB ----------------
constexpr size_t OF_FLAGS = 0;                  // 512*32*4 = 64KiB
constexpr size_t OF_BIAS4 = 65536;              // 2048 f32
constexpr size_t OF_BIASQ = 73728;              // 1536 f32
constexpr size_t OF_BTX   = 131072;             // Bt_x [2048][256] bf16 = 1MiB
constexpr size_t OF_BTH   = 1179648;            // Bt_h [2048][512] bf16 = 2MiB
constexpr size_t OF_BTQKV = 3276800;            // Bt_qkv [1536][512] bf16 = 1.5MiB
constexpr size_t OF_YQ    = (size_t)5  << 20;   // 32MiB
constexpr size_t OF_YK    = OF_YQ + ((size_t)32 << 20);
constexpr size_t OF_VT    = OF_YK + ((size_t)32 << 20);   // ends at 101MiB

// d_out scratch offsets (inside 64MiB decoded region; dead before decode writes)
constexpr size_t DOUT_LOUT = 0;                 // lout bf16 [32768][512] = 32MiB
constexpr size_t DOUT_XBF  = (size_t)32 << 20;  // xbf bf16 [32768][256] = 16MiB

// ---------------- helpers ----------------
__device__ inline s8 ldg8(const bf16* p){ return *(const s8*)p; }
__device__ inline short f2bs(float f){ return __builtin_bit_cast(short, __float2bfloat16(f)); }
__device__ inline float sigf(float x){ return 1.f/(1.f + __expf(-x)); }
__device__ inline float tanhf_(float x){ x = fminf(fmaxf(x, -15.f), 15.f); float e = __expf(2.f*x); return (e-1.f)/(e+1.f); }

// 16B fragment load that bypasses L1/L2 (sc0 sc1) via two relaxed agent-scope
// 8B atomic loads. Reads the IF$ coherence point directly, so NO per-step
// agent acquire fence (= per-XCD L2 invalidation) is needed before it.
__device__ inline s8 ldh16a(const bf16* p){
  const unsigned long long* q8 = (const unsigned long long*)p;
  unsigned long long lo = __hip_atomic_load(q8,     __ATOMIC_RELAXED, __HIP_MEMORY_SCOPE_AGENT);
  unsigned long long hi = __hip_atomic_load(q8 + 1, __ATOMIC_RELAXED, __HIP_MEMORY_SCOPE_AGENT);
  typedef __attribute__((ext_vector_type(2))) unsigned long long v2u64;
  v2u64 t; t.x = lo; t.y = hi;
  return __builtin_bit_cast(s8, t);
}

// ================= K0: pack weights/biases/x, zero flags =================
__global__ void k0_pack(const float* x,
                        const float* Wf,const float* Wi,const float* Wg,const float* Wo,
                        const float* bfv,const float* biv,const float* bgv,const float* bov,
                        const float* Wq,const float* Wk,const float* Wv,
                        const float* bqv,const float* bkv,const float* bvv,
                        bf16* xbf, bf16* btx, bf16* bth, bf16* btqkv,
                        float* bias4, float* biasq, int* flags)
{
  const float* WG[4] = {Wf, Wi, Wg, Wo};
  const float* BG[4] = {bfv, biv, bgv, bov};
  const float* WQ[3] = {Wq, Wk, Wv};
  const float* BQ[3] = {bqv, bkv, bvv};
  const long NX   = 8388608;   // 32768*256
  const long NBTH = 1048576;   // 2048*512
  const long NBTQ = 786432;    // 1536*512
  const long NBTX = 524288;    // 2048*256
  const long NF   = 16384;     // 512*32
  const long TOT  = NX + NBTH + NBTQ + NBTX + NF + 2048 + 1536;
  long stride = (long)gridDim.x * blockDim.x;
  for (long i = (long)blockIdx.x*blockDim.x + threadIdx.x; i < TOT; i += stride){
    if (i < NX){ xbf[i] = __float2bfloat16(x[i]); }
    else if (i < NX + NBTH){
      long j = i - NX; int n = (int)(j >> 9), k = (int)(j & 511);
      int g = n >> 9, hid = n & 511;
      bth[j] = __float2bfloat16(WG[g][(size_t)(256 + k)*512 + hid]);
    } else if (i < NX + NBTH + NBTQ){
      long j = i - NX - NBTH; int n = (int)(j >> 9), k = (int)(j & 511);
      int w = n >> 9, c = n & 511;
      btqkv[j] = __float2bfloat16(WQ[w][(size_t)k*512 + c]);
    } else if (i < NX + NBTH + NBTQ + NBTX){
      long j = i - NX - NBTH - NBTQ; int n = (int)(j >> 8), k = (int)(j & 255);
      int g = n >> 9, hid = n & 511;
      btx[j] = __float2bfloat16(WG[g][(size_t)k*512 + hid]);
    } else if (i < NX + NBTH + NBTQ + NBTX + NF){
      flags[i - NX - NBTH - NBTQ - NBTX] = 0;
    } else if (i < NX + NBTH + NBTQ + NBTX + NF + 2048){
      long j = i - NX - NBTH - NBTQ - NBTX - NF; int g = (int)(j >> 9), hid = (int)(j & 511);
      bias4[j] = BG[g][hid];
    } else {
      long j = i - NX - NBTH - NBTQ - NBTX - NF - 2048; int w = (int)(j >> 9), c = (int)(j & 511);
      biasq[j] = BQ[w][c];
    }
  }
}

// ================= K1: persistent LSTM recurrence (x-GEMM folded in) =====
// 32 blocks x 512 thr. Block ns owns hidden units [16ns,16ns+16) x 4 gates.
// W_h (128 VGPR) + W_x (64 VGPR) slices resident as B-fragments.
// Sync protocol (no per-step cache maintenance):
//   producer: h stores = relaxed agent atomics (sc0sc1 -> IF$), barrier drains
//             vmcnt(0), then RELAXED flag store (data already globally visible;
//             a RELEASE here would emit a per-step L2 writeback for nothing).
//   consumer: relaxed flag poll (bypass), then h loads as relaxed agent
//             atomics (bypass, read IF$ directly). No agent acquire fence ->
//             no per-step per-XCD L2 invalidation; xbf stays warm in L2.
__global__ __launch_bounds__(512) void k1_lstm(const bf16* xbf, const bf16* btx, const bf16* bth,
                                               const float* bias4, bf16* lout, int* flags,
                                               float* out_tail)
{
  int ns = blockIdx.x;
  int tid = threadIdx.x, w = tid >> 6, lane = tid & 63;
  int mt = w >> 1, nh = w & 1, lm = lane & 15, q = lane >> 4;
  __shared__ float pre[64][68];
  // resident B-fragments: 2 gates (2*nh, 2*nh+1)
  s8 Bh[2][16], Bx[2][8];
  #pragma unroll
  for (int i = 0; i < 2; ++i){
    const bf16* bph = bth + ((size_t)((2*nh+i)*512 + ns*16 + lm)) * 512;
    #pragma unroll
    for (int kk = 0; kk < 16; ++kk) Bh[i][kk] = ldg8(bph + kk*32 + q*8);
    const bf16* bpx = btx + ((size_t)((2*nh+i)*512 + ns*16 + lm)) * 256;
    #pragma unroll
    for (int kk = 0; kk < 8; ++kk) Bx[i][kk] = ldg8(bpx + kk*32 + q*8);
  }
  // elementwise cells: thread owns (b0, j0) and (b0, j0+1)
  int c0 = 2*tid, b0 = c0 >> 4, j0 = c0 & 15;
  float bs[8];
  #pragma unroll
  for (int g = 0; g < 4; ++g){
    bs[g]   = bias4[g*512 + ns*16 + j0];
    bs[4+g] = bias4[g*512 + ns*16 + j0 + 1];
  }
  float cs0 = 0.f, cs1 = 0.f;
  int budget = 1 << 22;   // poll bailout (prevents infinite hang)

  for (int t = 0; t < 512; ++t){
    // x-part GEMM (independent of recurrence -> before the poll)
    f4 acc[2] = {{0,0,0,0},{0,0,0,0}};
    const bf16* xr = xbf + ((size_t)(t*64 + mt*16 + lm)) * 256;
    #pragma unroll
    for (int kk = 0; kk < 8; ++kk){
      s8 A = ldg8(xr + kk*32 + q*8);
      acc[0] = MFMA16(A, Bx[0][kk], acc[0]);
      acc[1] = MFMA16(A, Bx[1][kk], acc[1]);
    }
    if (t > 0){
      int* fb = flags + (size_t)(t-1)*32;
      while (budget > 0){
        int v = 1;
        if (lane < 32) v = __hip_atomic_load(fb + lane, __ATOMIC_RELAXED, __HIP_MEMORY_SCOPE_AGENT);
        if (__ballot(v != 0) == ~0ull) break;
        budget--;
        __builtin_amdgcn_s_sleep(1);
      }
      // compiler-level ordering only (no L2 invalidation): h loads below
      // bypass the caches, so flag-visible => data-visible at IF$.
      __builtin_amdgcn_fence(__ATOMIC_ACQUIRE, "workgroup");
      const bf16* hr = lout + ((size_t)((t-1)*64 + mt*16 + lm)) * 512;
      #pragma unroll
      for (int kk = 0; kk < 16; ++kk){
        s8 A = ldh16a(hr + kk*32 + q*8);
        acc[0] = MFMA16(A, Bh[0][kk], acc[0]);
        acc[1] = MFMA16(A, Bh[1][kk], acc[1]);
      }
    }
    // pre-activations -> LDS
    #pragma unroll
    for (int i = 0; i < 2; ++i){
      int col = (2*nh+i)*16 + lm;
      #pragma unroll
      for (int r = 0; r < 4; ++r) pre[mt*16 + q*4 + r][col] = acc[i][r];
    }
    __syncthreads();
    // elementwise gates for 2 cells
    {
      float fh0 = pre[b0][ 0+j0] + bs[0], fh1 = pre[b0][ 0+j0+1] + bs[4];
      float ih0 = pre[b0][16+j0] + bs[1], ih1 = pre[b0][16+j0+1] + bs[5];
      float gh0 = pre[b0][32+j0] + bs[2], gh1 = pre[b0][32+j0+1] + bs[6];
      float oh0 = pre[b0][48+j0] + bs[3], oh1 = pre[b0][48+j0+1] + bs[7];
      cs0 = sigf(fh0)*cs0 + sigf(ih0)*tanhf_(gh0);
      cs1 = sigf(fh1)*cs1 + sigf(ih1)*tanhf_(gh1);
      float h0 = sigf(oh0)*tanhf_(cs0);
      float h1 = sigf(oh1)*tanhf_(cs1);
      unsigned hv = (unsigned)(unsigned short)f2bs(h0) | ((unsigned)(unsigned short)f2bs(h1) << 16);
      __hip_atomic_store((unsigned*)(lout + ((size_t)(t*64 + b0))*512 + ns*16 + j0),
                         hv, __ATOMIC_RELAXED, __HIP_MEMORY_SCOPE_AGENT);
      if (t == 511){
        float* hx = out_tail + (size_t)b0*512 + ns*16 + j0;
        hx[0] = h0; hx[1] = h1;
        float* cx = out_tail + 32768 + (size_t)b0*512 + ns*16 + j0;
        cx[0] = cs0; cx[1] = cs1;
      }
    }
    __syncthreads();   // barrier implies vmcnt(0): all h stores drained to IF$
    if (tid == 0)
      __hip_atomic_store(flags + (size_t)t*32 + ns, 1, __ATOMIC_RELAXED, __HIP_MEMORY_SCOPE_AGENT);
  }
}

// ================= K2: fused QKV GEMM (N=1536), V written transposed =====
// grid (24, 512), 512 thr. Tile 64x64, K=512.
__global__ __launch_bounds__(512) void k2_qkv(const bf16* lout, const bf16* btqkv, const float* biasq,
                                              bf16* yq, bf16* yk, bf16* vt)
{
  int nb = blockIdx.x, rb = blockIdx.y;
  int tid = threadIdx.x, w = tid >> 6, lane = tid & 63;
  int mt = w >> 1, nh = w & 1, lm = lane & 15, q = lane >> 4;
  int row = rb*64 + mt*16 + lm;
  f4 acc[2] = {{0,0,0,0},{0,0,0,0}};
  const bf16* ap  = lout + (size_t)row * 512;
  const bf16* bp0 = btqkv + ((size_t)(nb*64 + (2*nh+0)*16 + lm)) * 512;
  const bf16* bp1 = btqkv + ((size_t)(nb*64 + (2*nh+1)*16 + lm)) * 512;
  #pragma unroll
  for (int kk = 0; kk < 16; ++kk){
    int kb = kk*32 + q*8;
    s8 A = ldg8(ap + kb);
    acc[0] = MFMA16(A, ldg8(bp0 + kb), acc[0]);
    acc[1] = MFMA16(A, ldg8(bp1 + kb), acc[1]);
  }
  #pragma unroll
  for (int i = 0; i < 2; ++i){
    int e = nb*64 + (2*nh+i)*16 + lm;
    float bias = biasq[e];
    #pragma unroll
    for (int r = 0; r < 4; ++r){
      int rr = rb*64 + mt*16 + q*4 + r;
      bf16 v = __float2bfloat16(acc[i][r] + bias);
      if (e < 512)        yq[(size_t)rr*512 + e] = v;
      else if (e < 1024)  yk[(size_t)rr*512 + (e-512)] = v;
      else {
        int d = e - 1024, hh = d >> 7, dh = d & 127;
        vt[((size_t)((rr >> 9)*4 + hh)*128 + dh)*512 + (rr & 511)] = v;
      }
    }
  }
}

// ================= K3: fused scores + softmax + PV -> decoded ============
// grid (8 rowblocks, 256 bh), 256 thr (4 waves, wave = 16-row Q tile).
// LDS: 64KiB union — sK[128][128] during scores, sP[64][512] (XOR-swizzled)
// for the P layout round-trip into the PV MFMA A-operand.
__global__ __launch_bounds__(256) void k3_attn(const bf16* yq, const bf16* yk, const bf16* vt,
                                               float* dec)
{
  int rb = blockIdx.x, bh = blockIdx.y;
  int b1 = bh >> 2, hh = bh & 3;
  int tid = threadIdx.x, w = tid >> 6, lane = tid & 63, lm = lane & 15, q = lane >> 4;
  __shared__ short sbuf[32768];             // 64KiB
  short (*sK)[128] = (short(*)[128])sbuf;   // 16384 shorts = 32KiB
  // A fragments (Q rows), K=128 -> 4 k-steps
  s8 Af[4];
  const bf16* apr = yq + ((size_t)(b1*512 + rb*64 + w*16 + lm))*512 + hh*128;
  #pragma unroll
  for (int kk = 0; kk < 4; ++kk) Af[kk] = ldg8(apr + kk*32 + q*8);
  f4 acc[32];
  #pragma unroll
  for (int nt = 0; nt < 32; ++nt) acc[nt] = (f4){0,0,0,0};

  for (int ch = 0; ch < 4; ++ch){
    __syncthreads();
    #pragma unroll
    for (int it = 0; it < 8; ++it){
      int lin = tid + it*256;              // 0..2047
      int srow = lin >> 4, seg = lin & 15; // 16 segs of 8 bf16
      int pseg = seg ^ (srow & 15);        // swizzle
      *(s8*)&sK[srow][pseg*8] =
        ldg8(yk + ((size_t)(b1*512 + ch*128 + srow))*512 + hh*128 + seg*8);
    }
    __syncthreads();
    #pragma unroll
    for (int ntl = 0; ntl < 8; ++ntl){
      int nt = ch*8 + ntl;
      int brow = ntl*16 + lm;
      #pragma unroll
      for (int kk = 0; kk < 4; ++kk){
        int c = (kk*4 + q) ^ lm;           // de-swizzle
        s8 Bfr = *(const s8*)&sK[brow][c*8];
        acc[nt] = MFMA16(Af[kk], Bfr, acc[nt]);
      }
    }
  }
  // softmax over the full 512-col row (16 lanes x 32 n-tiles)
  const float scale = 0.08838834764831845f;  // 1/sqrt(128)
  float mx[4], sm[4];
  #pragma unroll
  for (int r = 0; r < 4; ++r){
    float m = -1e30f;
    #pragma unroll
    for (int nt = 0; nt < 32; ++nt) m = fmaxf(m, acc[nt][r]);
    mx[r] = m;
  }
  #pragma unroll
  for (int d = 1; d < 16; d <<= 1){
    #pragma unroll
    for (int r = 0; r < 4; ++r) mx[r] = fmaxf(mx[r], __shfl_xor(mx[r], d, 64));
  }
  #pragma unroll
  for (int r = 0; r < 4; ++r){
    float s = 0.f;
    #pragma unroll
    for (int nt = 0; nt < 32; ++nt){
      float e = __expf(scale * (acc[nt][r] - mx[r]));
      acc[nt][r] = e; s += e;
    }
    sm[r] = s;
  }
  #pragma unroll
  for (int d = 1; d < 16; d <<= 1){
    #pragma unroll
    for (int r = 0; r < 4; ++r) sm[r] += __shfl_xor(sm[r], d, 64);
  }
  float inv[4];
  #pragma unroll
  for (int r = 0; r < 4; ++r) inv[r] = 1.f / sm[r];

  __syncthreads();   // all sK reads done before sP overwrites the buffer
  // P tile -> LDS, XOR-swizzled 16B chunks: phys = row*512 + ((col>>3)^(row&15))*8 + (col&7)
  #pragma unroll
  for (int nt = 0; nt < 32; ++nt){
    #pragma unroll
    for (int r = 0; r < 4; ++r){
      int rowp = w*16 + q*4 + r, col = nt*16 + lm;
      sbuf[rowp*512 + (((col >> 3) ^ (rowp & 15))*8) + (col & 7)] =
        f2bs(acc[nt][r] * inv[r]);
    }
  }
  // PV: wave-local (each wave reads only rows it wrote) — no barrier needed
  f4 o[8];
  #pragma unroll
  for (int n2 = 0; n2 < 8; ++n2) o[n2] = (f4){0,0,0,0};
  int rowa = w*16 + lm;
  #pragma unroll
  for (int kk = 0; kk < 16; ++kk){
    s8 A = *(const s8*)&sbuf[rowa*512 + (((kk*4 + q) ^ (rowa & 15))*8)];
    #pragma unroll
    for (int n2 = 0; n2 < 8; ++n2){
      s8 Bfr = ldg8(vt + ((size_t)(bh*128 + n2*16 + lm))*512 + kk*32 + q*8);
      o[n2] = MFMA16(A, Bfr, o[n2]);
    }
  }
  #pragma unroll
  for (int n2 = 0; n2 < 8; ++n2){
    int d = n2*16 + lm;
    #pragma unroll
    for (int r = 0; r < 4; ++r){
      int s1 = rb*64 + w*16 + q*4 + r;
      dec[((size_t)s1*64 + b1)*512 + hh*128 + d] = o[n2][r];
    }
  }
}

// ================= launcher =================
extern "C" void kernel_launch(void* const* d_in, const int* in_sizes, int n_in,
                              void* d_out, int out_size, void* d_ws, size_t ws_size,
                              hipStream_t stream)
{
  const float* x   = (const float*)d_in[0];
  const float* Wf  = (const float*)d_in[1];  const float* bfv = (const float*)d_in[2];
  const float* Wi  = (const float*)d_in[3];  const float* biv = (const float*)d_in[4];
  const float* Wg  = (const float*)d_in[5];  const float* bgv = (const float*)d_in[6];
  const float* Wo  = (const float*)d_in[7];  const float* bov = (const float*)d_in[8];
  const float* Wq  = (const float*)d_in[9];  const float* bqv = (const float*)d_in[10];
  const float* Wk  = (const float*)d_in[11]; const float* bkv = (const float*)d_in[12];
  const float* Wv  = (const float*)d_in[13]; const float* bvv = (const float*)d_in[14];

  char* ws = (char*)d_ws;
  int*   flags = (int*)  (ws + OF_FLAGS);
  float* bias4 = (float*)(ws + OF_BIAS4);
  float* biasq = (float*)(ws + OF_BIASQ);
  bf16*  btx   = (bf16*) (ws + OF_BTX);
  bf16*  bth   = (bf16*) (ws + OF_BTH);
  bf16*  btqkv = (bf16*) (ws + OF_BTQKV);
  bf16*  yq    = (bf16*) (ws + OF_YQ);
  bf16*  yk    = (bf16*) (ws + OF_YK);
  bf16*  vt    = (bf16*) (ws + OF_VT);

  char* outc = (char*)d_out;
  bf16*  lout = (bf16*)(outc + DOUT_LOUT);   // dead before decode writes
  bf16*  xbf  = (bf16*)(outc + DOUT_XBF);    // dead before decode writes
  float* out  = (float*)d_out;

  hipLaunchKernelGGL(k0_pack, dim3(2048), dim3(256), 0, stream,
                     x, Wf, Wi, Wg, Wo, bfv, biv, bgv, bov, Wq, Wk, Wv, bqv, bkv, bvv,
                     xbf, btx, bth, btqkv, bias4, biasq, flags);
  hipLaunchKernelGGL(k1_lstm, dim3(32), dim3(512), 0, stream,
                     xbf, btx, bth, bias4, lout, flags, out + DEC_SZ);
  hipLaunchKernelGGL(k2_qkv, dim3(24, 512), dim3(512), 0, stream, lout, btqkv, biasq, yq, yk, vt);
  hipLaunchKernelGGL(k3_attn, dim3(8, 256), dim3(256), 0, stream, yq, yk, vt, out);
}

// Round 2
// 4332.193 us; speedup vs baseline: 1.3988x; 1.3988x over previous
//
#include <hip/hip_runtime.h>
#include <hip/hip_bf16.h>

typedef __attribute__((ext_vector_type(8))) short s8;
typedef __attribute__((ext_vector_type(4))) float f4;

using bf16 = __hip_bfloat16;

#define MFMA16(a,b,c) __builtin_amdgcn_mfma_f32_16x16x32_bf16((a),(b),(c),0,0,0)

// HW_REG_XCC_ID (id=20), offset 0, width 4  ->  simm16 = id | (off<<6) | ((w-1)<<11)
#define GETREG_XCC_ID (20 | (0 << 6) | (3 << 11))

// ---------------- sizes ----------------
constexpr int SS = 512, BBATCH = 64, HIDN = 512;
constexpr size_t DEC_SZ = (size_t)SS * BBATCH * HIDN;  // 16777216 f32 = 64MiB

// ---------------- ws layout (bytes), total 101 MiB ----------------
constexpr size_t OF_FLAGS = 0;                  // 512*32*4 = 64KiB
constexpr size_t OF_BIAS4 = 65536;              // 2048 f32
constexpr size_t OF_BIASQ = 73728;              // 1536 f32  (ends 79872)
constexpr size_t OF_CLAIM = 81920;              // 1 int (worker-slot counter)
constexpr size_t OF_BTX   = 131072;             // Bt_x [2048][256] bf16 = 1MiB
constexpr size_t OF_BTH   = 1179648;            // Bt_h [2048][512] bf16 = 2MiB
constexpr size_t OF_BTQKV = 3276800;            // Bt_qkv [1536][512] bf16 = 1.5MiB
constexpr size_t OF_YQ    = (size_t)5  << 20;   // 32MiB
constexpr size_t OF_YK    = OF_YQ + ((size_t)32 << 20);
constexpr size_t OF_VT    = OF_YK + ((size_t)32 << 20);   // ends at 101MiB

// d_out scratch offsets (inside 64MiB decoded region; dead before decode writes)
constexpr size_t DOUT_LOUT = 0;                 // lout bf16 [32768][512] = 32MiB
constexpr size_t DOUT_XBF  = (size_t)32 << 20;  // xbf bf16 [32768][256] = 16MiB

// ---------------- helpers ----------------
__device__ inline s8 ldg8(const bf16* p){ return *(const s8*)p; }
__device__ inline short f2bs(float f){ return __builtin_bit_cast(short, __float2bfloat16(f)); }
__device__ inline float sigf(float x){ return 1.f/(1.f + __expf(-x)); }
__device__ inline float tanhf_(float x){ x = fminf(fmaxf(x, -15.f), 15.f); float e = __expf(2.f*x); return (e-1.f)/(e+1.f); }

// ================= K0: pack weights/biases/x, zero flags =================
__global__ void k0_pack(const float* x,
                        const float* Wf,const float* Wi,const float* Wg,const float* Wo,
                        const float* bfv,const float* biv,const float* bgv,const float* bov,
                        const float* Wq,const float* Wk,const float* Wv,
                        const float* bqv,const float* bkv,const float* bvv,
                        bf16* xbf, bf16* btx, bf16* bth, bf16* btqkv,
                        float* bias4, float* biasq, int* flags, int* claim)
{
  const float* WG[4] = {Wf, Wi, Wg, Wo};
  const float* BG[4] = {bfv, biv, bgv, bov};
  const float* WQ[3] = {Wq, Wk, Wv};
  const float* BQ[3] = {bqv, bkv, bvv};
  const long NX   = 8388608;   // 32768*256
  const long NBTH = 1048576;   // 2048*512
  const long NBTQ = 786432;    // 1536*512
  const long NBTX = 524288;    // 2048*256
  const long NF   = 16384;     // 512*32
  const long TOT  = NX + NBTH + NBTQ + NBTX + NF + 2048 + 1536 + 1;
  long stride = (long)gridDim.x * blockDim.x;
  for (long i = (long)blockIdx.x*blockDim.x + threadIdx.x; i < TOT; i += stride){
    if (i < NX){ xbf[i] = __float2bfloat16(x[i]); }
    else if (i < NX + NBTH){
      long j = i - NX; int n = (int)(j >> 9), k = (int)(j & 511);
      int g = n >> 9, hid = n & 511;
      bth[j] = __float2bfloat16(WG[g][(size_t)(256 + k)*512 + hid]);
    } else if (i < NX + NBTH + NBTQ){
      long j = i - NX - NBTH; int n = (int)(j >> 9), k = (int)(j & 511);
      int w = n >> 9, c = n & 511;
      btqkv[j] = __float2bfloat16(WQ[w][(size_t)k*512 + c]);
    } else if (i < NX + NBTH + NBTQ + NBTX){
      long j = i - NX - NBTH - NBTQ; int n = (int)(j >> 8), k = (int)(j & 255);
      int g = n >> 9, hid = n & 511;
      btx[j] = __float2bfloat16(WG[g][(size_t)k*512 + hid]);
    } else if (i < NX + NBTH + NBTQ + NBTX + NF){
      flags[i - NX - NBTH - NBTQ - NBTX] = 0;
    } else if (i < NX + NBTH + NBTQ + NBTX + NF + 2048){
      long j = i - NX - NBTH - NBTQ - NBTX - NF; int g = (int)(j >> 9), hid = (int)(j & 511);
      bias4[j] = BG[g][hid];
    } else if (i < NX + NBTH + NBTQ + NBTX + NF + 2048 + 1536){
      long j = i - NX - NBTH - NBTQ - NBTX - NF - 2048; int w = (int)(j >> 9), c = (int)(j & 511);
      biasq[j] = BQ[w][c];
    } else {
      claim[0] = 0;
    }
  }
}

// ================= K1: persistent LSTM recurrence, XCD0-pinned ===========
// 512 blocks launched; only the first 32 blocks that land on XCD 0 (ground
// truth via s_getreg(HW_REG_XCC_ID)) claim worker slots; the rest exit.
// All cross-block traffic (h tiles + flags) then stays inside XCD0's 4MiB
// L2 (~200cy) instead of round-tripping the IF$ (~600-900cy + cache ops):
//   producer: plain h stores (L1 is write-through -> land in L2);
//             __syncthreads() implies vmcnt(0) drain; plain flag store.
//   consumer: flag poll via sc0-only loads (bypass L1, hit L2 — agent
//             atomics would add sc1 and read a stale IF$ copy instead);
//             h loads are plain cached loads — safe because every lout/flag
//             address is fresh per timestep (never in any reader's L1/L2).
// No buffer_inv / sc1 anywhere in the step loop; x stays warm in L2.
__global__ __launch_bounds__(512) void k1_lstm(const bf16* xbf, const bf16* btx, const bf16* bth,
                                               const float* bias4, bf16* lout, int* flags,
                                               int* claim, float* out_tail)
{
  __shared__ int s_ns;
  int xcc = (int)(__builtin_amdgcn_s_getreg(GETREG_XCC_ID) & 15);
  if (threadIdx.x == 0){
    int nsl = -1;
    if (xcc == 0){
      nsl = __hip_atomic_fetch_add(claim, 1, __ATOMIC_RELAXED, __HIP_MEMORY_SCOPE_AGENT);
      if (nsl >= 32) nsl = -1;
    }
    s_ns = nsl;
  }
  __syncthreads();
  int ns = s_ns;
  if (ns < 0) return;

  int tid = threadIdx.x, w = tid >> 6, lane = tid & 63;
  int mt = w >> 1, nh = w & 1, lm = lane & 15, q = lane >> 4;
  __shared__ float pre[64][68];
  // resident B-fragments: 2 gates (2*nh, 2*nh+1)
  s8 Bh[2][16], Bx[2][8];
  #pragma unroll
  for (int i = 0; i < 2; ++i){
    const bf16* bph = bth + ((size_t)((2*nh+i)*512 + ns*16 + lm)) * 512;
    #pragma unroll
    for (int kk = 0; kk < 16; ++kk) Bh[i][kk] = ldg8(bph + kk*32 + q*8);
    const bf16* bpx = btx + ((size_t)((2*nh+i)*512 + ns*16 + lm)) * 256;
    #pragma unroll
    for (int kk = 0; kk < 8; ++kk) Bx[i][kk] = ldg8(bpx + kk*32 + q*8);
  }
  // elementwise cells: thread owns (b0, j0) and (b0, j0+1)
  int c0 = 2*tid, b0 = c0 >> 4, j0 = c0 & 15;
  float bs[8];
  #pragma unroll
  for (int g = 0; g < 4; ++g){
    bs[g]   = bias4[g*512 + ns*16 + j0];
    bs[4+g] = bias4[g*512 + ns*16 + j0 + 1];
  }
  float cs0 = 0.f, cs1 = 0.f;
  int budget = 1 << 20;   // poll bailout (prevents infinite hang; loud failure)

  for (int t = 0; t < 512; ++t){
    // x-part GEMM (independent of recurrence -> before the poll)
    f4 acc[2] = {{0,0,0,0},{0,0,0,0}};
    const bf16* xr = xbf + ((size_t)(t*64 + mt*16 + lm)) * 256;
    #pragma unroll
    for (int kk = 0; kk < 8; ++kk){
      s8 A = ldg8(xr + kk*32 + q*8);
      acc[0] = MFMA16(A, Bx[0][kk], acc[0]);
      acc[1] = MFMA16(A, Bx[1][kk], acc[1]);
    }
    if (t > 0){
      const int* fp = flags + (size_t)(t-1)*32 + (lane & 31);
      while (budget > 0){
        int v;
        asm volatile("global_load_dword %0, %1, off sc0\n\ts_waitcnt vmcnt(0)"
                     : "=v"(v) : "v"(fp) : "memory");
        if (__ballot(v != 0 || lane >= 32) == ~0ull) break;
        budget--;
        __builtin_amdgcn_s_sleep(1);
      }
      // compiler reorder barrier only; no cache maintenance needed (same-XCD L2)
      __builtin_amdgcn_fence(__ATOMIC_ACQUIRE, "workgroup");
      const bf16* hr = lout + ((size_t)((t-1)*64 + mt*16 + lm)) * 512;
      #pragma unroll
      for (int kk = 0; kk < 16; ++kk){
        s8 A = ldg8(hr + kk*32 + q*8);
        acc[0] = MFMA16(A, Bh[0][kk], acc[0]);
        acc[1] = MFMA16(A, Bh[1][kk], acc[1]);
      }
    }
    // pre-activations -> LDS
    #pragma unroll
    for (int i = 0; i < 2; ++i){
      int col = (2*nh+i)*16 + lm;
      #pragma unroll
      for (int r = 0; r < 4; ++r) pre[mt*16 + q*4 + r][col] = acc[i][r];
    }
    __syncthreads();
    // elementwise gates for 2 cells
    {
      float fh0 = pre[b0][ 0+j0] + bs[0], fh1 = pre[b0][ 0+j0+1] + bs[4];
      float ih0 = pre[b0][16+j0] + bs[1], ih1 = pre[b0][16+j0+1] + bs[5];
      float gh0 = pre[b0][32+j0] + bs[2], gh1 = pre[b0][32+j0+1] + bs[6];
      float oh0 = pre[b0][48+j0] + bs[3], oh1 = pre[b0][48+j0+1] + bs[7];
      cs0 = sigf(fh0)*cs0 + sigf(ih0)*tanhf_(gh0);
      cs1 = sigf(fh1)*cs1 + sigf(ih1)*tanhf_(gh1);
      float h0 = sigf(oh0)*tanhf_(cs0);
      float h1 = sigf(oh1)*tanhf_(cs1);
      unsigned hv = (unsigned)(unsigned short)f2bs(h0) | ((unsigned)(unsigned short)f2bs(h1) << 16);
      // plain store: write-through L1 -> lands in XCD0 L2 (the sync domain)
      *(unsigned*)(lout + ((size_t)(t*64 + b0))*512 + ns*16 + j0) = hv;
      if (t == 511){
        float* hx = out_tail + (size_t)b0*512 + ns*16 + j0;
        hx[0] = h0; hx[1] = h1;
        float* cx = out_tail + 32768 + (size_t)b0*512 + ns*16 + j0;
        cx[0] = cs0; cx[1] = cs1;
      }
    }
    __syncthreads();   // implies vmcnt(0): all h stores drained to L2
    if (tid == 0)
      *(volatile int*)(flags + (size_t)t*32 + ns) = 1;
  }
}

// ================= K2: fused QKV GEMM (N=1536), V written transposed =====
// grid (24, 512), 512 thr. Tile 64x64, K=512.
__global__ __launch_bounds__(512) void k2_qkv(const bf16* lout, const bf16* btqkv, const float* biasq,
                                              bf16* yq, bf16* yk, bf16* vt)
{
  int nb = blockIdx.x, rb = blockIdx.y;
  int tid = threadIdx.x, w = tid >> 6, lane = tid & 63;
  int mt = w >> 1, nh = w & 1, lm = lane & 15, q = lane >> 4;
  int row = rb*64 + mt*16 + lm;
  f4 acc[2] = {{0,0,0,0},{0,0,0,0}};
  const bf16* ap  = lout + (size_t)row * 512;
  const bf16* bp0 = btqkv + ((size_t)(nb*64 + (2*nh+0)*16 + lm)) * 512;
  const bf16* bp1 = btqkv + ((size_t)(nb*64 + (2*nh+1)*16 + lm)) * 512;
  #pragma unroll
  for (int kk = 0; kk < 16; ++kk){
    int kb = kk*32 + q*8;
    s8 A = ldg8(ap + kb);
    acc[0] = MFMA16(A, ldg8(bp0 + kb), acc[0]);
    acc[1] = MFMA16(A, ldg8(bp1 + kb), acc[1]);
  }
  #pragma unroll
  for (int i = 0; i < 2; ++i){
    int e = nb*64 + (2*nh+i)*16 + lm;
    float bias = biasq[e];
    #pragma unroll
    for (int r = 0; r < 4; ++r){
      int rr = rb*64 + mt*16 + q*4 + r;
      bf16 v = __float2bfloat16(acc[i][r] + bias);
      if (e < 512)        yq[(size_t)rr*512 + e] = v;
      else if (e < 1024)  yk[(size_t)rr*512 + (e-512)] = v;
      else {
        int d = e - 1024, hh = d >> 7, dh = d & 127;
        vt[((size_t)((rr >> 9)*4 + hh)*128 + dh)*512 + (rr & 511)] = v;
      }
    }
  }
}

// ================= K3: fused scores + softmax + PV -> decoded ============
// grid (8 rowblocks, 256 bh), 256 thr (4 waves, wave = 16-row Q tile).
// LDS: 64KiB union — sK[128][128] during scores, sP[64][512] (XOR-swizzled)
// for the P layout round-trip into the PV MFMA A-operand.
__global__ __launch_bounds__(256) void k3_attn(const bf16* yq, const bf16* yk, const bf16* vt,
                                               float* dec)
{
  int rb = blockIdx.x, bh = blockIdx.y;
  int b1 = bh >> 2, hh = bh & 3;
  int tid = threadIdx.x, w = tid >> 6, lane = tid & 63, lm = lane & 15, q = lane >> 4;
  __shared__ short sbuf[32768];             // 64KiB
  short (*sK)[128] = (short(*)[128])sbuf;   // 16384 shorts = 32KiB
  // A fragments (Q rows), K=128 -> 4 k-steps
  s8 Af[4];
  const bf16* apr = yq + ((size_t)(b1*512 + rb*64 + w*16 + lm))*512 + hh*128;
  #pragma unroll
  for (int kk = 0; kk < 4; ++kk) Af[kk] = ldg8(apr + kk*32 + q*8);
  f4 acc[32];
  #pragma unroll
  for (int nt = 0; nt < 32; ++nt) acc[nt] = (f4){0,0,0,0};

  for (int ch = 0; ch < 4; ++ch){
    __syncthreads();
    #pragma unroll
    for (int it = 0; it < 8; ++it){
      int lin = tid + it*256;              // 0..2047
      int srow = lin >> 4, seg = lin & 15; // 16 segs of 8 bf16
      int pseg = seg ^ (srow & 15);        // swizzle
      *(s8*)&sK[srow][pseg*8] =
        ldg8(yk + ((size_t)(b1*512 + ch*128 + srow))*512 + hh*128 + seg*8);
    }
    __syncthreads();
    #pragma unroll
    for (int ntl = 0; ntl < 8; ++ntl){
      int nt = ch*8 + ntl;
      int brow = ntl*16 + lm;
      #pragma unroll
      for (int kk = 0; kk < 4; ++kk){
        int c = (kk*4 + q) ^ lm;           // de-swizzle
        s8 Bfr = *(const s8*)&sK[brow][c*8];
        acc[nt] = MFMA16(Af[kk], Bfr, acc[nt]);
      }
    }
  }
  // softmax over the full 512-col row (16 lanes x 32 n-tiles)
  const float scale = 0.08838834764831845f;  // 1/sqrt(128)
  float mx[4], sm[4];
  #pragma unroll
  for (int r = 0; r < 4; ++r){
    float m = -1e30f;
    #pragma unroll
    for (int nt = 0; nt < 32; ++nt) m = fmaxf(m, acc[nt][r]);
    mx[r] = m;
  }
  #pragma unroll
  for (int d = 1; d < 16; d <<= 1){
    #pragma unroll
    for (int r = 0; r < 4; ++r) mx[r] = fmaxf(mx[r], __shfl_xor(mx[r], d, 64));
  }
  #pragma unroll
  for (int r = 0; r < 4; ++r){
    float s = 0.f;
    #pragma unroll
    for (int nt = 0; nt < 32; ++nt){
      float e = __expf(scale * (acc[nt][r] - mx[r]));
      acc[nt][r] = e; s += e;
    }
    sm[r] = s;
  }
  #pragma unroll
  for (int d = 1; d < 16; d <<= 1){
    #pragma unroll
    for (int r = 0; r < 4; ++r) sm[r] += __shfl_xor(sm[r], d, 64);
  }
  float inv[4];
  #pragma unroll
  for (int r = 0; r < 4; ++r) inv[r] = 1.f / sm[r];

  __syncthreads();   // all sK reads done before sP overwrites the buffer
  // P tile -> LDS, XOR-swizzled 16B chunks: phys = row*512 + ((col>>3)^(row&15))*8 + (col&7)
  #pragma unroll
  for (int nt = 0; nt < 32; ++nt){
    #pragma unroll
    for (int r = 0; r < 4; ++r){
      int rowp = w*16 + q*4 + r, col = nt*16 + lm;
      sbuf[rowp*512 + (((col >> 3) ^ (rowp & 15))*8) + (col & 7)] =
        f2bs(acc[nt][r] * inv[r]);
    }
  }
  // PV: wave-local (each wave reads only rows it wrote) — no barrier needed
  f4 o[8];
  #pragma unroll
  for (int n2 = 0; n2 < 8; ++n2) o[n2] = (f4){0,0,0,0};
  int rowa = w*16 + lm;
  #pragma unroll
  for (int kk = 0; kk < 16; ++kk){
    s8 A = *(const s8*)&sbuf[rowa*512 + (((kk*4 + q) ^ (rowa & 15))*8)];
    #pragma unroll
    for (int n2 = 0; n2 < 8; ++n2){
      s8 Bfr = ldg8(vt + ((size_t)(bh*128 + n2*16 + lm))*512 + kk*32 + q*8);
      o[n2] = MFMA16(A, Bfr, o[n2]);
    }
  }
  #pragma unroll
  for (int n2 = 0; n2 < 8; ++n2){
    int d = n2*16 + lm;
    #pragma unroll
    for (int r = 0; r < 4; ++r){
      int s1 = rb*64 + w*16 + q*4 + r;
      dec[((size_t)s1*64 + b1)*512 + hh*128 + d] = o[n2][r];
    }
  }
}

// ================= launcher =================
extern "C" void kernel_launch(void* const* d_in, const int* in_sizes, int n_in,
                              void* d_out, int out_size, void* d_ws, size_t ws_size,
                              hipStream_t stream)
{
  const float* x   = (const float*)d_in[0];
  const float* Wf  = (const float*)d_in[1];  const float* bfv = (const float*)d_in[2];
  const float* Wi  = (const float*)d_in[3];  const float* biv = (const float*)d_in[4];
  const float* Wg  = (const float*)d_in[5];  const float* bgv = (const float*)d_in[6];
  const float* Wo  = (const float*)d_in[7];  const float* bov = (const float*)d_in[8];
  const float* Wq  = (const float*)d_in[9];  const float* bqv = (const float*)d_in[10];
  const float* Wk  = (const float*)d_in[11]; const float* bkv = (const float*)d_in[12];
  const float* Wv  = (const float*)d_in[13]; const float* bvv = (const float*)d_in[14];

  char* ws = (char*)d_ws;
  int*   flags = (int*)  (ws + OF_FLAGS);
  float* bias4 = (float*)(ws + OF_BIAS4);
  float* biasq = (float*)(ws + OF_BIASQ);
  int*   claim = (int*)  (ws + OF_CLAIM);
  bf16*  btx   = (bf16*) (ws + OF_BTX);
  bf16*  bth   = (bf16*) (ws + OF_BTH);
  bf16*  btqkv = (bf16*) (ws + OF_BTQKV);
  bf16*  yq    = (bf16*) (ws + OF_YQ);
  bf16*  yk    = (bf16*) (ws + OF_YK);
  bf16*  vt    = (bf16*) (ws + OF_VT);

  char* outc = (char*)d_out;
  bf16*  lout = (bf16*)(outc + DOUT_LOUT);   // dead before decode writes
  bf16*  xbf  = (bf16*)(outc + DOUT_XBF);    // dead before decode writes
  float* out  = (float*)d_out;

  hipLaunchKernelGGL(k0_pack, dim3(2048), dim3(256), 0, stream,
                     x, Wf, Wi, Wg, Wo, bfv, biv, bgv, bov, Wq, Wk, Wv, bqv, bkv, bvv,
                     xbf, btx, bth, btqkv, bias4, biasq, flags, claim);
  hipLaunchKernelGGL(k1_lstm, dim3(512), dim3(512), 0, stream,
                     xbf, btx, bth, bias4, lout, flags, claim, out + DEC_SZ);
  hipLaunchKernelGGL(k2_qkv, dim3(24, 512), dim3(512), 0, stream, lout, btqkv, biasq, yq, yk, vt);
  hipLaunchKernelGGL(k3_attn, dim3(8, 256), dim3(256), 0, stream, yq, yk, vt, out);
}